// Round 4
// baseline (191.591 us; speedup 1.0000x reference)
//
#include <hip/hip_runtime.h>

// DynamicMaskHead: 128 instances, per-instance MLP 10->8->8->1 over 160x160 px.
// features: fp32 [1, 128*10, 160, 160]  -> [128][10][25600]
// params:   fp32 [128, 169]  layout: w0[80] w1[64] w2[8] b0[8] b1[8] b2[1]
// out:      fp32 [128, 1, 160, 160]   (R3 post-mortem: comparison is fp32;
//                                      the bf16-exact stub error came from a
//                                      bf16-quantized *reference*, not output)
//
// Memory-bound: 131 MB read + 13 MB write -> ~23 us at 6.3 TB/s achievable.

#define N_INST 128
#define C_IN   10
#define CH     8
#define HW     25600   // 160*160
#define PPT    4       // pixels per thread
#define BLK    256
#define CHUNKS 25      // 25600 / (256*4)

__global__ __launch_bounds__(BLK, 4)
void DynamicMaskHead_kernel(const float* __restrict__ feat,
                            const float* __restrict__ params,
                            float* __restrict__ out)
{
    __shared__ float sp[169];
    const int inst = blockIdx.y;
    const int tid  = threadIdx.x;

    if (tid < 169) sp[tid] = params[inst * 169 + tid];
    __syncthreads();

    const int p0 = blockIdx.x * (BLK * PPT) + tid * PPT;
    const float* fb = feat + (size_t)inst * C_IN * HW + p0;

    // All 10 channel loads issued up front (16 B each, coalesced).
    float4 raw[C_IN];
#pragma unroll
    for (int k = 0; k < C_IN; ++k)
        raw[k] = *(const float4*)(fb + (size_t)k * HW);

    // Layer 1: h1 = relu(W0 x + b0); W0[o][k]=sp[o*10+k], b0=sp[152+o]
    float h1[CH][PPT];
#pragma unroll
    for (int o = 0; o < CH; ++o) {
        const float b = sp[152 + o];
#pragma unroll
        for (int j = 0; j < PPT; ++j) h1[o][j] = b;
    }
#pragma unroll
    for (int k = 0; k < C_IN; ++k) {
        const float xv[PPT] = { raw[k].x, raw[k].y, raw[k].z, raw[k].w };
#pragma unroll
        for (int o = 0; o < CH; ++o) {
            const float w = sp[o * 10 + k];
#pragma unroll
            for (int j = 0; j < PPT; ++j) h1[o][j] = fmaf(w, xv[j], h1[o][j]);
        }
    }
#pragma unroll
    for (int o = 0; o < CH; ++o)
#pragma unroll
        for (int j = 0; j < PPT; ++j) h1[o][j] = fmaxf(h1[o][j], 0.f);

    // Layer 2: h2 = relu(W1 h1 + b1); W1[o][k]=sp[80+o*8+k], b1=sp[160+o]
    float h2[CH][PPT];
#pragma unroll
    for (int o = 0; o < CH; ++o) {
        const float b = sp[160 + o];
#pragma unroll
        for (int j = 0; j < PPT; ++j) h2[o][j] = b;
    }
#pragma unroll
    for (int k = 0; k < CH; ++k) {
#pragma unroll
        for (int o = 0; o < CH; ++o) {
            const float w = sp[80 + o * 8 + k];
#pragma unroll
            for (int j = 0; j < PPT; ++j) h2[o][j] = fmaf(w, h1[k][j], h2[o][j]);
        }
    }
#pragma unroll
    for (int o = 0; o < CH; ++o)
#pragma unroll
        for (int j = 0; j < PPT; ++j) h2[o][j] = fmaxf(h2[o][j], 0.f);

    // Layer 3: out = W2 h2 + b2; W2[k]=sp[144+k], b2=sp[168]
    float ov[PPT];
#pragma unroll
    for (int j = 0; j < PPT; ++j) ov[j] = sp[168];
#pragma unroll
    for (int k = 0; k < CH; ++k) {
        const float w = sp[144 + k];
#pragma unroll
        for (int j = 0; j < PPT; ++j) ov[j] = fmaf(w, h2[k][j], ov[j]);
    }

    float4 res;
    res.x = ov[0]; res.y = ov[1]; res.z = ov[2]; res.w = ov[3];
    *(float4*)(out + (size_t)inst * HW + p0) = res;
}

extern "C" void kernel_launch(void* const* d_in, const int* in_sizes, int n_in,
                              void* d_out, int out_size, void* d_ws, size_t ws_size,
                              hipStream_t stream) {
    const float* feat   = (const float*)d_in[0];
    const float* params = (const float*)d_in[1];
    float* out          = (float*)d_out;

    dim3 grid(CHUNKS, N_INST);
    dim3 block(BLK);
    hipLaunchKernelGGL(DynamicMaskHead_kernel, grid, block, 0, stream,
                       feat, params, out);
}

// Round 5
// 185.231 us; speedup vs baseline: 1.0343x; 1.0343x over previous
//
#include <hip/hip_runtime.h>

// DynamicMaskHead: 128 instances, per-instance MLP 10->8->8->1 over 160x160 px.
// features: fp32 [1, 128*10, 160, 160] -> [128][10][25600]
// params:   fp32 [128, 169]  w0[80] w1[64] w2[8] b0[8] b1[8] b2[1]
// out:      fp32 [128, 1, 160, 160]
//
// Roofline: 131 MB read + 13 MB write ≈ 23 us at 6.3 TB/s.
// R4 post-mortem: kernel <74.8 us (absent from rocprof top-5; bench 191.6 us
// includes ~150 us of harness ws-poison/input-restore fills). This round:
// spill-proof register budget (two 5-channel load batches, peak ~70 VGPR),
// launch_bounds(256,2) so the allocator is never forced under 128, and
// nontemporal loads/stores (single-use streams, keep L2/L3 clean).

#define N_INST 128
#define C_IN   10
#define CH     8
#define HW     25600   // 160*160
#define PPT    4       // pixels per thread
#define BLK    256
#define CHUNKS 25      // 25600 / (256*4)

typedef float f4 __attribute__((ext_vector_type(4)));

__global__ __launch_bounds__(BLK, 2)
void DynamicMaskHead_kernel(const float* __restrict__ feat,
                            const float* __restrict__ params,
                            float* __restrict__ out)
{
    __shared__ float sp[169];
    const int inst = blockIdx.y;
    const int tid  = threadIdx.x;

    if (tid < 169) sp[tid] = params[inst * 169 + tid];
    __syncthreads();

    const int p0 = blockIdx.x * (BLK * PPT) + tid * PPT;
    const float* fb = feat + (size_t)inst * C_IN * HW + p0;

    // Layer-1 accumulators, init with bias b0 = sp[152+o]
    float h1[CH][PPT];
#pragma unroll
    for (int o = 0; o < CH; ++o) {
        const float b = sp[152 + o];
#pragma unroll
        for (int j = 0; j < PPT; ++j) h1[o][j] = b;
    }

    // Two batches of 5 channels: 5 nontemporal 16B loads in flight,
    // peak raw regs = 20 VGPR (spill-proof).
    f4 raw[5];
#pragma unroll
    for (int half = 0; half < 2; ++half) {
        const int kb = half * 5;
#pragma unroll
        for (int k = 0; k < 5; ++k)
            raw[k] = __builtin_nontemporal_load(
                (const f4*)(fb + (size_t)(kb + k) * HW));
#pragma unroll
        for (int k = 0; k < 5; ++k) {
            const float xv[PPT] = { raw[k].x, raw[k].y, raw[k].z, raw[k].w };
#pragma unroll
            for (int o = 0; o < CH; ++o) {
                const float w = sp[o * 10 + (kb + k)];
#pragma unroll
                for (int j = 0; j < PPT; ++j)
                    h1[o][j] = fmaf(w, xv[j], h1[o][j]);
            }
        }
    }
#pragma unroll
    for (int o = 0; o < CH; ++o)
#pragma unroll
        for (int j = 0; j < PPT; ++j) h1[o][j] = fmaxf(h1[o][j], 0.f);

    // Layer 2: h2 = relu(W1 h1 + b1); W1[o][k]=sp[80+o*8+k], b1=sp[160+o]
    float h2[CH][PPT];
#pragma unroll
    for (int o = 0; o < CH; ++o) {
        const float b = sp[160 + o];
#pragma unroll
        for (int j = 0; j < PPT; ++j) h2[o][j] = b;
    }
#pragma unroll
    for (int k = 0; k < CH; ++k) {
#pragma unroll
        for (int o = 0; o < CH; ++o) {
            const float w = sp[80 + o * 8 + k];
#pragma unroll
            for (int j = 0; j < PPT; ++j) h2[o][j] = fmaf(w, h1[k][j], h2[o][j]);
        }
    }
#pragma unroll
    for (int o = 0; o < CH; ++o)
#pragma unroll
        for (int j = 0; j < PPT; ++j) h2[o][j] = fmaxf(h2[o][j], 0.f);

    // Layer 3: out = W2 h2 + b2; W2[k]=sp[144+k], b2=sp[168]
    float ov[PPT];
#pragma unroll
    for (int j = 0; j < PPT; ++j) ov[j] = sp[168];
#pragma unroll
    for (int k = 0; k < CH; ++k) {
        const float w = sp[144 + k];
#pragma unroll
        for (int j = 0; j < PPT; ++j) ov[j] = fmaf(w, h2[k][j], ov[j]);
    }

    f4 res = { ov[0], ov[1], ov[2], ov[3] };
    __builtin_nontemporal_store(res, (f4*)(out + (size_t)inst * HW + p0));
}

extern "C" void kernel_launch(void* const* d_in, const int* in_sizes, int n_in,
                              void* d_out, int out_size, void* d_ws, size_t ws_size,
                              hipStream_t stream) {
    const float* feat   = (const float*)d_in[0];
    const float* params = (const float*)d_in[1];
    float* out          = (float*)d_out;

    dim3 grid(CHUNKS, N_INST);
    dim3 block(BLK);
    hipLaunchKernelGGL(DynamicMaskHead_kernel, grid, block, 0, stream,
                       feat, params, out);
}